// Round 9
// baseline (13967.624 us; speedup 1.0000x reference)
//
#include <hip/hip_runtime.h>

#define NL 4000
#define NC 8000
#define EMB 128
#define ROWC0 4096           // clause region start
#define NRP 12288            // padded total rows (384 panels x 32)
#define NRREAL (ROWC0 + NC)  // 12096 rows with data
#define TSTEPS 30
#define LCHUNK 80
#define NCHUNK 50
#define GBLK 384             // persistent blocks = panels
#define TBLK 128             // 2 waves/block
#define PROWS 32             // rows per panel
#define NLITPAN 125          // 4000/32 lit panels

typedef __attribute__((ext_vector_type(8))) short bf16x8;
typedef __attribute__((ext_vector_type(4))) float f32x4;

__device__ __forceinline__ short f2bf(float x) {
    union { float f; unsigned u; } v; v.f = x;
    unsigned r = v.u + 0x7fffu + ((v.u >> 16) & 1u);
    return (short)(r >> 16);
}
__device__ __forceinline__ float bf2f(short s) {
    union { unsigned u; float f; } v; v.u = ((unsigned)(unsigned short)s) << 16;
    return v.f;
}
__device__ __forceinline__ float sigf(float x) { return 1.f / (1.f + expf(-x)); }
__device__ __forceinline__ float2 h2f2(unsigned u) {
    union { unsigned v; _Float16 h[2]; } x; x.v = u;
    return make_float2((float)x.h[0], (float)x.h[1]);
}
__device__ __forceinline__ void gload16(const void* g, void* l) {
    __builtin_amdgcn_global_load_lds(
        (const __attribute__((address_space(1))) unsigned int*)g,
        (__attribute__((address_space(3))) unsigned int*)l, 16, 0, 0);
}

struct P {
    short *HAh, *HAl, *HBh, *HBl; float *CA, *CB;
    short *msgsH, *msgsL; _Float16* X;
    short *H1h, *H1l, *H2h, *H2l;
    float* accum; float* out; int* bar;
    const float *L_init, *C_init;
    const int *Lp, *Li, *Tp, *Ti;
    const short *W1hL, *W1lL, *W1hC, *W1lC;
    const short *W2hL, *W2lL, *W2hC, *W2lC;
    const short *W3hL, *W3lL, *W3hC, *W3lC;
    const short *WihhL, *WihlL, *WhhhL, *WhhlL;
    const short *WihhC, *WihlC, *WhhhC, *WhhlC;
    const short *V1h, *V1l, *V2h, *V2l;
    const float *b1L, *b1C, *b2L, *b2C, *b3L, *b3C, *LbL, *LbC;
    const float *Vb1, *Vb2, *VW3, *Vb3;
};

// Device-scope grid barrier (G16: device atomics + fences; L1/L2 flushed by
// __threadfence). All blocks co-resident by capacity arithmetic (see launch).
__device__ __forceinline__ void gbar(int* bar, int target) {
    __syncthreads();
    if (threadIdx.x == 0) {
        __threadfence();                 // release: drain writes device-wide
        atomicAdd(bar, 1);
        while (atomicAdd(bar, 0) < target) __builtin_amdgcn_s_sleep(2);
        __threadfence();                 // acquire: invalidate stale caches
    }
    __syncthreads();
}

// ---------------------------------------------------------------------------
// 32x128 GEMM tile (2-wave team), R7-verified pipeline with MR=2.
// OUTM: 1 = split-bf16 out (+relu), 4 = fp16 out, 3 = fused LSTM epilogue.
// ---------------------------------------------------------------------------
template<int KS, int OUTM, bool TWOA, bool RELU>
__device__ void gemm_tile(
    int row0, int c0,
    const short* __restrict__ A1h, const short* __restrict__ A1l,
    const short* __restrict__ A2h, const short* __restrict__ A2l,
    const short* __restrict__ B1hL, const short* __restrict__ B1lL,
    const short* __restrict__ B1hC, const short* __restrict__ B1lC,
    const short* __restrict__ B2hL, const short* __restrict__ B2lL,
    const short* __restrict__ B2hC, const short* __restrict__ B2lC,
    const float* __restrict__ biasL, const float* __restrict__ biasC,
    short* __restrict__ OH, short* __restrict__ OL, float* __restrict__ OF,
    const float* __restrict__ Cold, float* __restrict__ Cnew,
    int Freal, int Fstore,
    short* sAh, short* sAl, short* sBh, short* sBl)
{
    constexpr int KIT = KS / 32;
    constexpr int NIT = (TWOA ? 2 : 1) * KIT;
    const bool isC = (row0 >= ROWC0);
    const int t = threadIdx.x;
    const int lane = t & 63;
    const int wc = t >> 6;                // col-wave 0..1
    const int l15 = lane & 15;

    __syncthreads();                       // protect LDS reuse across tiles

    f32x4 acc[2][4] = {};

    auto stage = [&](int buf, int it) {
        const int ph = it / KIT;
        const int kc = (it - ph * KIT) * 32;
        const short *Ah, *Al, *Bh, *Bl;
        if (TWOA && ph) {
            Ah = A2h; Al = A2l;
            Bh = isC ? B2hC : B2hL; Bl = isC ? B2lC : B2lL;
        } else {
            Ah = A1h; Al = A1l;
            Bh = isC ? B1hC : B1hL; Bl = isC ? B1lC : B1lL;
        }
        {   // A: 32 rows x 4 slots = 128 chunks / 128 thr
            int c = t;
            int row = c >> 2, slot = c & 3;
            int gk = kc + ((slot ^ ((row >> 1) & 3)) << 3);
            size_t gi = (size_t)(row0 + row) * KS + gk;
            gload16(Ah + gi, &sAh[buf * 1024 + c * 8]);
            gload16(Al + gi, &sAl[buf * 1024 + c * 8]);
        }
#pragma unroll
        for (int q = 0; q < 4; ++q) {      // B: 128 rows x 4 slots
            int c = q * TBLK + t;
            int row = c >> 2, slot = c & 3;
            int gk = kc + ((slot ^ ((row >> 1) & 3)) << 3);
            size_t gi = (size_t)(c0 + row) * KS + gk;
            gload16(Bh + gi, &sBh[buf * 4096 + c * 8]);
            gload16(Bl + gi, &sBl[buf * 4096 + c * 8]);
        }
    };

    stage(0, 0);
    asm volatile("s_waitcnt vmcnt(0)" ::: "memory");
    __syncthreads();

    int cur = 0;
    for (int it = 0; it < NIT; ++it) {
        if (it + 1 < NIT) stage(cur ^ 1, it + 1);

        bf16x8 af[2][2], bfr[4][2];
#pragma unroll
        for (int s = 0; s < 2; ++s) {
            int row = s * 16 + l15;
            int slot = (lane >> 4) ^ ((row >> 1) & 3);
            int idx = cur * 1024 + row * 32 + slot * 8;
            af[s][0] = *(const bf16x8*)&sAh[idx];
            af[s][1] = *(const bf16x8*)&sAl[idx];
        }
#pragma unroll
        for (int u = 0; u < 4; ++u) {
            int colr = wc * 64 + u * 16 + l15;
            int slotb = (lane >> 4) ^ ((colr >> 1) & 3);
            int idxb = cur * 4096 + colr * 32 + slotb * 8;
            bfr[u][0] = *(const bf16x8*)&sBh[idxb];
            bfr[u][1] = *(const bf16x8*)&sBl[idxb];
        }
#pragma unroll
        for (int s = 0; s < 2; ++s)
#pragma unroll
            for (int u = 0; u < 4; ++u) {
                acc[s][u] = __builtin_amdgcn_mfma_f32_16x16x32_bf16(af[s][0], bfr[u][0], acc[s][u], 0, 0, 0);
                acc[s][u] = __builtin_amdgcn_mfma_f32_16x16x32_bf16(af[s][0], bfr[u][1], acc[s][u], 0, 0, 0);
                acc[s][u] = __builtin_amdgcn_mfma_f32_16x16x32_bf16(af[s][1], bfr[u][0], acc[s][u], 0, 0, 0);
            }

        if (it + 1 < NIT) {
            asm volatile("s_waitcnt vmcnt(0)" ::: "memory");
            __syncthreads();
            cur ^= 1;
        }
    }

    if (OUTM != 3) {
#pragma unroll
        for (int u = 0; u < 4; ++u) {
            int col = c0 + wc * 64 + u * 16 + l15;
            if (col >= Fstore) continue;
            float bv = (col < Freal) ? (isC ? biasC[col] : biasL[col]) : 0.f;
#pragma unroll
            for (int s = 0; s < 2; ++s)
#pragma unroll
                for (int j = 0; j < 4; ++j) {
                    int row = row0 + s * 16 + (lane >> 4) * 4 + j;
                    float v = acc[s][u][j] + bv;
                    if (RELU) v = fmaxf(v, 0.f);
                    size_t oi = (size_t)row * Fstore + col;
                    if (OUTM == 1) {
                        short h = f2bf(v);
                        OH[oi] = h;
                        OL[oi] = f2bf(v - bf2f(h));
                    } else {
                        ((_Float16*)OF)[oi] = (_Float16)v;
                    }
                }
        }
    } else {
        const int q = lane & 3;
#pragma unroll
        for (int u = 0; u < 4; ++u) {
            int colp = c0 + wc * 64 + u * 16 + l15;
            int wrr = (colp & 3) * 128 + (colp >> 2);
            float bv = isC ? biasC[wrr] : biasL[wrr];
            int j = colp >> 2;
#pragma unroll
            for (int s = 0; s < 2; ++s) {
                float ii = 0.f, ff = 0.f, gg = 0.f, oo = 0.f;
#pragma unroll
                for (int r2 = 0; r2 < 4; ++r2) {
                    float v0 = acc[s][u][r2] + bv;
                    float x1 = __shfl_xor(v0, 1);
                    float x2 = __shfl_xor(v0, 2);
                    float x3 = __shfl_xor(v0, 3);
                    float iv = (q == 0) ? v0 : (q == 1) ? x1 : (q == 2) ? x2 : x3;
                    float fv = (q == 0) ? x1 : (q == 1) ? v0 : (q == 2) ? x3 : x2;
                    float gv = (q == 0) ? x2 : (q == 1) ? x3 : (q == 2) ? v0 : x1;
                    float ov = (q == 0) ? x3 : (q == 1) ? x2 : (q == 2) ? x1 : v0;
                    if (q == r2) { ii = iv; ff = fv; gg = gv; oo = ov; }
                }
                int row = row0 + s * 16 + (lane >> 4) * 4 + q;
                size_t ci = (size_t)row * 128 + j;
                float c2 = sigf(ff) * Cold[ci] + sigf(ii) * tanhf(gg);
                float h2 = sigf(oo) * tanhf(c2);
                Cnew[ci] = c2;
                short h = f2bf(h2);
                OH[ci] = h;
                OL[ci] = f2bf(h2 - bf2f(h));
            }
        }
    }
}

// SpMM for a 2-row group (one row per wave), fp16 X in, split-bf16 msgs out.
__device__ void spmm_rows(int rbase, const P& p)
{
    const int r = rbase + (threadIdx.x >> 6);
    const int cp = (threadIdx.x & 63) * 2;
    const _Float16* X = p.X;
    float s0 = 0.f, s1 = 0.f;
    bool valid = true;
    if (r < NL) {
        int b = p.Lp[r], e = p.Lp[r + 1];
        int i = b;
        for (; i + 3 < e; i += 4) {
            unsigned u0 = *(const unsigned*)&X[(size_t)(ROWC0 + p.Li[i]) * EMB + cp];
            unsigned u1 = *(const unsigned*)&X[(size_t)(ROWC0 + p.Li[i + 1]) * EMB + cp];
            unsigned u2 = *(const unsigned*)&X[(size_t)(ROWC0 + p.Li[i + 2]) * EMB + cp];
            unsigned u3 = *(const unsigned*)&X[(size_t)(ROWC0 + p.Li[i + 3]) * EMB + cp];
            float2 v0 = h2f2(u0), v1 = h2f2(u1), v2 = h2f2(u2), v3 = h2f2(u3);
            s0 += v0.x + v1.x + v2.x + v3.x;
            s1 += v0.y + v1.y + v2.y + v3.y;
        }
        for (; i < e; ++i) {
            float2 v = h2f2(*(const unsigned*)&X[(size_t)(ROWC0 + p.Li[i]) * EMB + cp]);
            s0 += v.x; s1 += v.y;
        }
    } else if (r >= ROWC0 && r < NRREAL) {
        int c = r - ROWC0;
        int b = p.Tp[c], e = p.Tp[c + 1];
        int i = b;
        for (; i + 3 < e; i += 4) {
            unsigned u0 = *(const unsigned*)&X[(size_t)p.Ti[i] * EMB + cp];
            unsigned u1 = *(const unsigned*)&X[(size_t)p.Ti[i + 1] * EMB + cp];
            unsigned u2 = *(const unsigned*)&X[(size_t)p.Ti[i + 2] * EMB + cp];
            unsigned u3 = *(const unsigned*)&X[(size_t)p.Ti[i + 3] * EMB + cp];
            float2 v0 = h2f2(u0), v1 = h2f2(u1), v2 = h2f2(u2), v3 = h2f2(u3);
            s0 += v0.x + v1.x + v2.x + v3.x;
            s1 += v0.y + v1.y + v2.y + v3.y;
        }
        for (; i < e; ++i) {
            float2 v = h2f2(*(const unsigned*)&X[(size_t)p.Ti[i] * EMB + cp]);
            s0 += v.x; s1 += v.y;
        }
    } else {
        valid = false;
    }
    if (valid) {
        size_t oi = (size_t)r * EMB + cp;
        short h0 = f2bf(s0), h1 = f2bf(s1);
        *(unsigned*)&p.msgsH[oi] = (unsigned)(unsigned short)h0 | ((unsigned)(unsigned short)h1 << 16);
        short l0 = f2bf(s0 - bf2f(h0)), l1 = f2bf(s1 - bf2f(h1));
        *(unsigned*)&p.msgsL[oi] = (unsigned)(unsigned short)l0 | ((unsigned)(unsigned short)l1 << 16);
    }
}

// ---------------------------------------------------------------------------
// Persistent mega-kernel: block b owns panel b (32 rows). Per step only 2
// grid barriers (X-ready RAW; X-overwrite WAR) — MLP chain, spmm output, and
// LSTM are panel-local.
// ---------------------------------------------------------------------------
__global__ __launch_bounds__(TBLK) void mega(P p)
{
    __shared__ short sAh[2 * 1024];
    __shared__ short sAl[2 * 1024];
    __shared__ short sBh[2 * 4096];
    __shared__ short sBl[2 * 4096];
    const int t = threadIdx.x;
    const int panel = blockIdx.x;
    const int row0 = panel * PROWS;
    const size_t NE = (size_t)NRP * EMB;
    int nbar = 0;

    // init (grid-strided)
    for (size_t idx = (size_t)blockIdx.x * TBLK + t; idx < NE; idx += (size_t)GBLK * TBLK) {
        int r = (int)(idx >> 7);
        int e = (int)(idx & 127);
        float h = 0.f;
        if (r < NL) h = p.L_init[e];
        else if (r >= ROWC0 && r < NRREAL) h = p.C_init[e];
        short hh = f2bf(h);
        p.HAh[idx] = hh;
        p.HAl[idx] = f2bf(h - bf2f(hh));
        p.CA[idx] = 0.f;
        if (r >= NRREAL || (r >= NL && r < ROWC0)) { p.msgsH[idx] = 0; p.msgsL[idx] = 0; }
    }
    gbar(p.bar, (++nbar) * GBLK);

    for (int step = 0; step < TSTEPS; ++step) {
        const short* Hch = (step & 1) ? p.HBh : p.HAh;
        const short* Hcl = (step & 1) ? p.HBl : p.HAl;
        short* Hnh = (step & 1) ? p.HAh : p.HBh;
        short* Hnl = (step & 1) ? p.HAl : p.HBl;
        const float* Ccur = (step & 1) ? p.CB : p.CA;
        float* Cnxt = (step & 1) ? p.CA : p.CB;

        // Phase A (panel-local): G1 -> G2 -> G3
#pragma unroll 1
        for (int ct = 0; ct < 4; ++ct)
            gemm_tile<128, 1, false, true>(row0, ct * 128,
                Hch, Hcl, nullptr, nullptr,
                p.W1hL, p.W1lL, p.W1hC, p.W1lC, nullptr, nullptr, nullptr, nullptr,
                p.b1L, p.b1C, p.H1h, p.H1l, nullptr, nullptr, nullptr,
                400, 416, sAh, sAl, sBh, sBl);
#pragma unroll 1
        for (int ct = 0; ct < 2; ++ct)
            gemm_tile<416, 1, false, true>(row0, ct * 128,
                p.H1h, p.H1l, nullptr, nullptr,
                p.W2hL, p.W2lL, p.W2hC, p.W2lC, nullptr, nullptr, nullptr, nullptr,
                p.b2L, p.b2C, p.H2h, p.H2l, nullptr, nullptr, nullptr,
                200, 224, sAh, sAl, sBh, sBl);
        gemm_tile<224, 4, false, false>(row0, 0,
            p.H2h, p.H2l, nullptr, nullptr,
            p.W3hL, p.W3lL, p.W3hC, p.W3lC, nullptr, nullptr, nullptr, nullptr,
            p.b3L, p.b3C, nullptr, nullptr, (float*)p.X, nullptr, nullptr,
            128, 128, sAh, sAl, sBh, sBl);

        gbar(p.bar, (++nbar) * GBLK);          // X complete (RAW)

        // Phase B (panel-local): spmm for own rows, then fused gates+LSTM
#pragma unroll 1
        for (int rr = 0; rr < PROWS; rr += 2)
            spmm_rows(row0 + rr, p);

        gbar(p.bar, (++nbar) * GBLK);          // all X reads done (WAR)

#pragma unroll 1
        for (int ct = 0; ct < 4; ++ct)
            gemm_tile<128, 3, true, false>(row0, ct * 128,
                p.msgsH, p.msgsL, Hch, Hcl,
                p.WihhL, p.WihlL, p.WihhC, p.WihlC,
                p.WhhhL, p.WhhlL, p.WhhhC, p.WhhlC,
                p.LbL, p.LbC, Hnh, Hnl, nullptr, Ccur, Cnxt,
                512, 512, sAh, sAl, sBh, sBl);
    }

    // Vote MLP (lit panels only; final H in HA after 30 steps)
    if (panel < NLITPAN) {
#pragma unroll 1
        for (int ct = 0; ct < 4; ++ct)
            gemm_tile<128, 1, false, true>(row0, ct * 128,
                p.HAh, p.HAl, nullptr, nullptr,
                p.V1h, p.V1l, p.V1h, p.V1l, nullptr, nullptr, nullptr, nullptr,
                p.Vb1, p.Vb1, p.H1h, p.H1l, nullptr, nullptr, nullptr,
                400, 416, sAh, sAl, sBh, sBl);
#pragma unroll 1
        for (int ct = 0; ct < 2; ++ct)
            gemm_tile<416, 1, false, true>(row0, ct * 128,
                p.H1h, p.H1l, nullptr, nullptr,
                p.V2h, p.V2l, p.V2h, p.V2l, nullptr, nullptr, nullptr, nullptr,
                p.Vb2, p.Vb2, p.H2h, p.H2l, nullptr, nullptr, nullptr,
                200, 224, sAh, sAl, sBh, sBl);
        __syncthreads();
#pragma unroll 1
        for (int rr = 0; rr < PROWS; rr += 2) {
            int r = row0 + rr + (t >> 6);
            int lane = t & 63;
            float s = 0.f;
            const short* xh = &p.H2h[(size_t)r * 224];
            const short* xl = &p.H2l[(size_t)r * 224];
            for (int k = lane; k < 200; k += 64) s += (bf2f(xh[k]) + bf2f(xl[k])) * p.VW3[k];
#pragma unroll
            for (int o = 32; o > 0; o >>= 1) s += __shfl_down(s, o);
            if (lane == 0) {
                float v = 1.f / (1.f + expf(-(s + p.Vb3[0])));
                atomicAdd(p.accum, v);
            }
        }
    }
    gbar(p.bar, (++nbar) * GBLK);              // all votes accumulated
    if (blockIdx.x == 0 && t == 0) {
        float avg = p.accum[0] / (float)NL;
        p.out[0] = logf(avg / (1.f - avg));
    }
}

__global__ void reset_k(int* bar, float* accum)
{
    bar[0] = 0;
    accum[0] = 0.f;
}

struct SplitJobs {
    const float* src[12];
    short* dh[12]; short* dl[12];
    int rows[12], cols[12], prows[12], pcols[12], perm[12];
};

__global__ __launch_bounds__(256) void split_all(SplitJobs J)
{
    int j = blockIdx.y;
    int i = blockIdx.x * 256 + threadIdx.x;
    int pr = J.prows[j], pc = J.pcols[j];
    if (i >= pr * pc) return;
    int pp = i / pc, c = i - pp * pc;
    int r = J.perm[j] ? (((pp & 3) << 7) | (pp >> 2)) : pp;
    float v = (r < J.rows[j] && c < J.cols[j]) ? J.src[j][(size_t)r * J.cols[j] + c] : 0.f;
    short h = f2bf(v);
    J.dh[j][i] = h;
    J.dl[j][i] = f2bf(v - bf2f(h));
}

__global__ __launch_bounds__(256) void count_rows_L(const float* __restrict__ M, int* __restrict__ cnt)
{
    int l = blockIdx.x, t = threadIdx.x;
    int c_ = 0;
    for (int c = t; c < NC; c += 256) c_ += (M[(size_t)l * NC + c] != 0.f) ? 1 : 0;
#pragma unroll
    for (int off = 32; off > 0; off >>= 1) c_ += __shfl_down(c_, off);
    __shared__ int w[4];
    if ((t & 63) == 0) w[t >> 6] = c_;
    __syncthreads();
    if (t == 0) cnt[l] = w[0] + w[1] + w[2] + w[3];
}

__global__ __launch_bounds__(256) void scan_excl(const int* __restrict__ in, int* __restrict__ out, int n)
{
    const int t = threadIdx.x;
    const int per = (n + 255) >> 8;
    __shared__ int part[256];
    int s = 0;
    const int start = t * per;
    for (int i = 0; i < per; ++i) { int idx = start + i; if (idx < n) s += in[idx]; }
    part[t] = s;
    __syncthreads();
    for (int off = 1; off < 256; off <<= 1) {
        int v = (t >= off) ? part[t - off] : 0;
        __syncthreads();
        part[t] += v;
        __syncthreads();
    }
    int run = (t == 0) ? 0 : part[t - 1];
    for (int i = 0; i < per; ++i) {
        int idx = start + i;
        if (idx < n) { out[idx] = run; run += in[idx]; }
    }
    if (t == 255) out[n] = part[255];
}

__global__ __launch_bounds__(256) void fill_L(const float* __restrict__ M,
                                              const int* __restrict__ Lp, int* __restrict__ Lidx)
{
    int l = blockIdx.x, t = threadIdx.x, lane = t & 63, wid = t >> 6;
    __shared__ int wcnt[4];
    __shared__ int base;
    if (t == 0) base = Lp[l];
    __syncthreads();
    for (int c0 = 0; c0 < NC; c0 += 256) {
        int c = c0 + t;
        bool pr = (c < NC) && (M[(size_t)l * NC + c] != 0.f);
        unsigned long long m = __ballot(pr);
        if (lane == 0) wcnt[wid] = (int)__popcll(m);
        __syncthreads();
        int off = base;
        for (int w = 0; w < wid; ++w) off += wcnt[w];
        int rank = (int)__popcll(m & ((1ull << lane) - 1ull));
        if (pr) Lidx[off + rank] = c;
        __syncthreads();
        if (t == 0) base += wcnt[0] + wcnt[1] + wcnt[2] + wcnt[3];
        __syncthreads();
    }
}

__global__ __launch_bounds__(256) void count_T(const float* __restrict__ M, int* __restrict__ cnt2d)
{
    int s = blockIdx.y;
    int c = blockIdx.x * 256 + threadIdx.x;
    if (c >= NC) return;
    int n = 0;
    int l0 = s * LCHUNK, l1 = l0 + LCHUNK;
    for (int l = l0; l < l1; ++l) n += (M[(size_t)l * NC + c] != 0.f) ? 1 : 0;
    cnt2d[(size_t)s * NC + c] = n;
}

__global__ __launch_bounds__(256) void colscan_T(const int* __restrict__ cnt2d,
                                                 int* __restrict__ cum2d, int* __restrict__ cntT)
{
    int c = blockIdx.x * 256 + threadIdx.x;
    if (c >= NC) return;
    int run = 0;
    for (int s = 0; s < NCHUNK; ++s) {
        cum2d[(size_t)s * NC + c] = run;
        run += cnt2d[(size_t)s * NC + c];
    }
    cntT[c] = run;
}

__global__ __launch_bounds__(256) void fill_T(const float* __restrict__ M,
                                              const int* __restrict__ Tp, const int* __restrict__ cum2d,
                                              int* __restrict__ Tidx)
{
    int s = blockIdx.y;
    int c = blockIdx.x * 256 + threadIdx.x;
    if (c >= NC) return;
    int pos = Tp[c] + cum2d[(size_t)s * NC + c];
    int l0 = s * LCHUNK, l1 = l0 + LCHUNK;
    for (int l = l0; l < l1; ++l) {
        if (M[(size_t)l * NC + c] != 0.f) Tidx[pos++] = l;
    }
}

extern "C" void kernel_launch(void* const* d_in, const int* in_sizes, int n_in,
                              void* d_out, int out_size, void* d_ws, size_t ws_size,
                              hipStream_t stream)
{
    const float* M      = (const float*)d_in[0];
    const float* L_init = (const float*)d_in[1];
    const float* C_init = (const float*)d_in[2];
    const float* LC_W1 = (const float*)d_in[3];  const float* LC_b1 = (const float*)d_in[4];
    const float* LC_W2 = (const float*)d_in[5];  const float* LC_b2 = (const float*)d_in[6];
    const float* LC_W3 = (const float*)d_in[7];  const float* LC_b3 = (const float*)d_in[8];
    const float* CL_W1 = (const float*)d_in[9];  const float* CL_b1 = (const float*)d_in[10];
    const float* CL_W2 = (const float*)d_in[11]; const float* CL_b2 = (const float*)d_in[12];
    const float* CL_W3 = (const float*)d_in[13]; const float* CL_b3 = (const float*)d_in[14];
    const float* L_Wih = (const float*)d_in[15]; const float* L_Whh = (const float*)d_in[16];
    const float* L_b   = (const float*)d_in[17];
    const float* C_Wih = (const float*)d_in[18]; const float* C_Whh = (const float*)d_in[19];
    const float* C_b   = (const float*)d_in[20];
    const float* V_W1 = (const float*)d_in[21]; const float* V_b1 = (const float*)d_in[22];
    const float* V_W2 = (const float*)d_in[23]; const float* V_b2 = (const float*)d_in[24];
    const float* V_W3 = (const float*)d_in[25]; const float* V_b3 = (const float*)d_in[26];

    char* ws = (char*)d_ws;
    size_t off = 0;
    auto alloc = [&](size_t bytes) -> void* {
        void* pt = ws + off;
        off += (bytes + 255) & ~(size_t)255;
        return pt;
    };
    const size_t NE = (size_t)NRP * EMB;
    P p{};
    p.HAh = (short*)alloc(NE * 2); p.HAl = (short*)alloc(NE * 2);
    p.HBh = (short*)alloc(NE * 2); p.HBl = (short*)alloc(NE * 2);
    p.CA = (float*)alloc(NE * 4);  p.CB = (float*)alloc(NE * 4);
    p.msgsH = (short*)alloc(NE * 2); p.msgsL = (short*)alloc(NE * 2);
    p.X = (_Float16*)alloc(NE * 2);
    p.H1h = (short*)alloc((size_t)NRP * 416 * 2); p.H1l = (short*)alloc((size_t)NRP * 416 * 2);
    p.H2h = (short*)alloc((size_t)NRP * 224 * 2); p.H2l = (short*)alloc((size_t)NRP * 224 * 2);
    p.accum = (float*)alloc(256);
    p.bar = (int*)alloc(256);
    short* W1hL = (short*)alloc(512 * 128 * 2); short* W1lL = (short*)alloc(512 * 128 * 2);
    short* W1hC = (short*)alloc(512 * 128 * 2); short* W1lC = (short*)alloc(512 * 128 * 2);
    short* W2hL = (short*)alloc(256 * 416 * 2); short* W2lL = (short*)alloc(256 * 416 * 2);
    short* W2hC = (short*)alloc(256 * 416 * 2); short* W2lC = (short*)alloc(256 * 416 * 2);
    short* W3hL = (short*)alloc(128 * 224 * 2); short* W3lL = (short*)alloc(128 * 224 * 2);
    short* W3hC = (short*)alloc(128 * 224 * 2); short* W3lC = (short*)alloc(128 * 224 * 2);
    short* WihhL = (short*)alloc(512 * 128 * 2); short* WihlL = (short*)alloc(512 * 128 * 2);
    short* WhhhL = (short*)alloc(512 * 128 * 2); short* WhhlL = (short*)alloc(512 * 128 * 2);
    short* WihhC = (short*)alloc(512 * 128 * 2); short* WihlC = (short*)alloc(512 * 128 * 2);
    short* WhhhC = (short*)alloc(512 * 128 * 2); short* WhhlC = (short*)alloc(512 * 128 * 2);
    short* V1h = (short*)alloc(512 * 128 * 2); short* V1l = (short*)alloc(512 * 128 * 2);
    short* V2h = (short*)alloc(256 * 416 * 2); short* V2l = (short*)alloc(256 * 416 * 2);
    int* Lp   = (int*)alloc(4104 * 4);
    int* Tp   = (int*)alloc(8104 * 4);
    int* Lidx = (int*)alloc(1000000 * 4);
    int* Tidx = (int*)alloc(1000000 * 4);
    int* cnt2d = (int*)alloc((size_t)NCHUNK * NC * 4);
    int* cum2d = (int*)alloc((size_t)NCHUNK * NC * 4);
    int* cntL = (int*)alloc(4096 * 4);
    int* cntT = (int*)alloc(8192 * 4);
    (void)ws_size; (void)in_sizes; (void)n_in; (void)out_size;

    p.W1hL = W1hL; p.W1lL = W1lL; p.W1hC = W1hC; p.W1lC = W1lC;
    p.W2hL = W2hL; p.W2lL = W2lL; p.W2hC = W2hC; p.W2lC = W2lC;
    p.W3hL = W3hL; p.W3lL = W3lL; p.W3hC = W3hC; p.W3lC = W3lC;
    p.WihhL = WihhL; p.WihlL = WihlL; p.WhhhL = WhhhL; p.WhhlL = WhhlL;
    p.WihhC = WihhC; p.WihlC = WihlC; p.WhhhC = WhhhC; p.WhhlC = WhhlC;
    p.V1h = V1h; p.V1l = V1l; p.V2h = V2h; p.V2l = V2l;
    p.b1L = LC_b1; p.b1C = CL_b1; p.b2L = LC_b2; p.b2C = CL_b2;
    p.b3L = LC_b3; p.b3C = CL_b3; p.LbL = L_b; p.LbC = C_b;
    p.Vb1 = V_b1; p.Vb2 = V_b2; p.VW3 = V_W3; p.Vb3 = V_b3;
    p.L_init = L_init; p.C_init = C_init;
    p.Lp = Lp; p.Li = Lidx; p.Tp = Tp; p.Ti = Tidx;
    p.out = (float*)d_out;

    // CSR build
    count_rows_L<<<NL, 256, 0, stream>>>(M, cntL);
    scan_excl<<<1, 256, 0, stream>>>(cntL, Lp, NL);
    fill_L<<<NL, 256, 0, stream>>>(M, Lp, Lidx);
    {
        dim3 g((NC + 255) / 256, NCHUNK);
        count_T<<<g, 256, 0, stream>>>(M, cnt2d);
        colscan_T<<<(NC + 255) / 256, 256, 0, stream>>>(cnt2d, cum2d, cntT);
        scan_excl<<<1, 256, 0, stream>>>(cntT, Tp, NC);
        fill_T<<<g, 256, 0, stream>>>(M, Tp, cum2d, Tidx);
    }

    // merged weight split (1 dispatch)
    SplitJobs Jb{};
    auto setj = [&](int j, const float* s, short* dh, short* dl, int r, int c, int pr, int pc, int pm) {
        Jb.src[j] = s; Jb.dh[j] = dh; Jb.dl[j] = dl;
        Jb.rows[j] = r; Jb.cols[j] = c; Jb.prows[j] = pr; Jb.pcols[j] = pc; Jb.perm[j] = pm;
    };
    setj(0, LC_W1, W1hL, W1lL, 400, 128, 512, 128, 0);
    setj(1, CL_W1, W1hC, W1lC, 400, 128, 512, 128, 0);
    setj(2, LC_W2, W2hL, W2lL, 200, 400, 256, 416, 0);
    setj(3, CL_W2, W2hC, W2lC, 200, 400, 256, 416, 0);
    setj(4, LC_W3, W3hL, W3lL, 128, 200, 128, 224, 0);
    setj(5, CL_W3, W3hC, W3lC, 128, 200, 128, 224, 0);
    setj(6, L_Wih, WihhL, WihlL, 512, 128, 512, 128, 1);
    setj(7, L_Whh, WhhhL, WhhlL, 512, 128, 512, 128, 1);
    setj(8, C_Wih, WihhC, WihlC, 512, 128, 512, 128, 1);
    setj(9, C_Whh, WhhhC, WhhlC, 512, 128, 512, 128, 1);
    setj(10, V_W1, V1h, V1l, 400, 128, 512, 128, 0);
    setj(11, V_W2, V2h, V2l, 200, 400, 256, 416, 0);
    {
        dim3 g((106496 + 255) / 256, 12);
        split_all<<<g, 256, 0, stream>>>(Jb);
    }

    // barrier/accum reset, then the persistent mega-kernel (normal launch)
    reset_k<<<1, 1, 0, stream>>>(p.bar, p.accum);
    mega<<<GBLK, TBLK, 0, stream>>>(p);
}